// Round 2
// baseline (109.736 us; speedup 1.0000x reference)
//
#include <hip/hip_runtime.h>
#include <math.h>

// One wave (64 lanes) per ray; 4 rays per 256-thread block.
// Coarse: 1 sample/lane. Fine: 3 consecutive samples/lane.
// cumprod/cumsum -> wave shuffle scans. "sort" -> merge of two sorted lists
// (z_vals linspace + monotone inverse-CDF samples) via binary-search scatter.
// Inputs/outputs are float32 per the reference (setup_inputs uses jnp.float32).

#define RAYS   8192
#define SC     64
#define SFINE  192
#define HID    64
#define NEARP  2.0f
#define FARP   6.0f
#define EPS_T  1e-10f
#define EPS_W  1e-5f
#define F32EPS 1.1920929e-7f

__global__ __launch_bounds__(256) void nerf_kernel(
    const float* __restrict__ ro, const float* __restrict__ rd,
    const float* __restrict__ W1, const float* __restrict__ b1,
    const float* __restrict__ W2, const float* __restrict__ b2,
    float* __restrict__ out)
{
    // weights shared by all 4 waves: w1 row h = {W1[0..3][h]},{W1[4..5][h],b1[h],0}; w2 row h = W2[h][0..3]
    __shared__ float4 sW1[2 * HID];
    __shared__ float4 sW2[HID];
    __shared__ float  sCdf[4][64];   // 63 used
    __shared__ float  sZc [4][64];   // coarse z
    __shared__ float  sZs [4][128];  // fine z samples (sorted)
    __shared__ float  sZf [4][192];  // merged

    const int tid = threadIdx.x;
    if (tid < HID) {
        const int h = tid;
        float4 a, b, c;
        a.x = W1[0 * HID + h]; a.y = W1[1 * HID + h];
        a.z = W1[2 * HID + h]; a.w = W1[3 * HID + h];
        b.x = W1[4 * HID + h]; b.y = W1[5 * HID + h];
        b.z = b1[h];           b.w = 0.f;
        c.x = W2[h * 4 + 0];   c.y = W2[h * 4 + 1];
        c.z = W2[h * 4 + 2];   c.w = W2[h * 4 + 3];
        sW1[2 * h] = a; sW1[2 * h + 1] = b; sW2[h] = c;
    }
    __syncthreads();

    const int w    = tid >> 6;
    const int lane = tid & 63;
    const int ray  = blockIdx.x * 4 + w;

    const float ox = ro[ray * 3 + 0], oy = ro[ray * 3 + 1], oz = ro[ray * 3 + 2];
    const float dx = rd[ray * 3 + 0], dy = rd[ray * 3 + 1], dz = rd[ray * 3 + 2];
    const float norm = sqrtf(dx * dx + dy * dy + dz * dz);
    const float inv  = 1.f / norm;
    const float vx = dx * inv, vy = dy * inv, vz = dz * inv;
    const float bb0 = b2[0], bb1 = b2[1], bb2 = b2[2], bb3 = b2[3];

    // ---------------- coarse pass ----------------
    const float t0c = (float)lane * (1.0f / 63.0f);
    const float z   = NEARP * (1.0f - t0c) + FARP * t0c;
    sZc[w][lane] = z;

    const float cx = fmaf(z, dx, ox), cy = fmaf(z, dy, oy), cz = fmaf(z, dz, oz);
    float o0 = bb0, o1 = bb1, o2 = bb2, o3 = bb3;
#pragma unroll 4
    for (int h = 0; h < HID; ++h) {
        const float4 wa = sW1[2 * h], wb = sW1[2 * h + 1], wc = sW2[h];
        float hv = fmaf(vx, wa.w, fmaf(vy, wb.x, fmaf(vz, wb.y, wb.z)));
        hv = fmaf(cx, wa.x, fmaf(cy, wa.y, fmaf(cz, wa.z, hv)));
        hv = fmaxf(hv, 0.f);
        o0 = fmaf(hv, wc.x, o0); o1 = fmaf(hv, wc.y, o1);
        o2 = fmaf(hv, wc.z, o2); o3 = fmaf(hv, wc.w, o3);
    }
    const float r   = 1.f / (1.f + expf(-o0));
    const float g   = 1.f / (1.f + expf(-o1));
    const float bl  = 1.f / (1.f + expf(-o2));
    const float sig = fmaxf(o3, 0.f);

    // volrender (coarse)
    const float znext = __shfl_down(z, 1);                // lane63 -> self, dist 0 (unused)
    const float dist  = (znext - z) * norm;
    const float alpha = (lane < 63) ? (1.f - expf(-sig * dist)) : 1.f;
    const float vfac  = 1.f - alpha + EPS_T;
    float p = vfac;
#pragma unroll
    for (int off = 1; off < 64; off <<= 1) {              // inclusive product scan
        const float q = __shfl_up(p, off);
        if (lane >= off) p *= q;
    }
    float excl = __shfl_up(p, 1);
    if (lane == 0) excl = 1.f;
    const float wgt = alpha * excl;

    float sr = wgt * r, sg = wgt * g, sb = wgt * bl, sa = wgt, sd = wgt * z;
#pragma unroll
    for (int m = 1; m < 64; m <<= 1) {
        sr += __shfl_xor(sr, m); sg += __shfl_xor(sg, m); sb += __shfl_xor(sb, m);
        sa += __shfl_xor(sa, m); sd += __shfl_xor(sd, m);
    }
    const float c_r = sr + (1.f - sa), c_g = sg + (1.f - sa), c_b = sb + (1.f - sa), c_d = sd;

    // ---------------- inverse-CDF sampling ----------------
    const float wm  = __shfl_down(wgt, 1);                // lane l: weights[l+1]
    const float wmv = (lane < 62) ? wm : 0.f;             // weights[:,1:-1], 62 bins
    float wsum = wmv;
#pragma unroll
    for (int m = 1; m < 64; m <<= 1) wsum += __shfl_xor(wsum, m);
    const float pad  = fmaxf(0.f, EPS_W - wsum);
    const float wadj = wmv + pad * (1.0f / 62.0f);
    const float wsp  = wsum + pad;
    const float pdf  = (lane < 62) ? (wadj / wsp) : 0.f;
    float ps = pdf;
#pragma unroll
    for (int off = 1; off < 64; off <<= 1) {              // inclusive sum scan
        const float q = __shfl_up(ps, off);
        if (lane >= off) ps += q;
    }
    if (lane < 61)  sCdf[w][lane + 1] = fminf(1.f, ps);   // cdf[1..61]
    if (lane == 61) sCdf[w][0]  = 0.f;
    if (lane == 62) sCdf[w][62] = 1.f;
    __syncthreads();

    float zsv[2];
#pragma unroll
    for (int j = 0; j < 2; ++j) {
        const int f = lane * 2 + j;
        const float u = (float)f * ((1.0f - F32EPS) / 127.0f);
        int lo = 0, hi = 62;                              // cdf[0]=0<=u < 1=cdf[62]
        while (hi - lo > 1) {
            const int mid = (lo + hi) >> 1;
            if (sCdf[w][mid] <= u) lo = mid; else hi = mid;
        }
        const float c0 = sCdf[w][lo], c1 = sCdf[w][lo + 1];
        const float den = c1 - c0;
        float tt = (den > 0.f) ? (u - c0) / den : 0.f;
        tt = fminf(fmaxf(tt, 0.f), 1.f);
        // bins = z_mid, computed analytically from the same linspace formula
        const float ta = (float)lo * (1.0f / 63.0f);
        const float tb = (float)(lo + 1) * (1.0f / 63.0f);
        const float tc = (float)(lo + 2) * (1.0f / 63.0f);
        const float za = NEARP * (1.f - ta) + FARP * ta;
        const float zb = NEARP * (1.f - tb) + FARP * tb;
        const float zc2 = NEARP * (1.f - tc) + FARP * tc;
        const float bin0 = 0.5f * (za + zb), bin1 = 0.5f * (zb + zc2);
        const float zs = fmaf(tt, bin1 - bin0, bin0);
        zsv[j] = zs;
        sZs[w][f] = zs;
    }
    __syncthreads();

    // ---------------- merge (both lists sorted) ----------------
    {   // coarse element: pos = idx + count(B < a)   (A-priority on ties)
        int lo = 0, hi = 128;
        while (lo < hi) { const int mid = (lo + hi) >> 1; if (sZs[w][mid] < z) lo = mid + 1; else hi = mid; }
        sZf[w][lane + lo] = z;
    }
#pragma unroll
    for (int j = 0; j < 2; ++j) {   // sample element: pos = idx + count(A <= b)
        const float bv = zsv[j];
        const int f = lane * 2 + j;
        int lo = 0, hi = 64;
        while (lo < hi) { const int mid = (lo + hi) >> 1; if (sZc[w][mid] <= bv) lo = mid + 1; else hi = mid; }
        sZf[w][f + lo] = bv;
    }
    __syncthreads();

    // ---------------- fine pass: 3 samples/lane ----------------
    const float zf0 = sZf[w][3 * lane + 0];
    const float zf1 = sZf[w][3 * lane + 1];
    const float zf2 = sZf[w][3 * lane + 2];
    const float zn2 = sZf[w][min(3 * lane + 3, 191)];     // lane63 value unused

    const float cx0 = fmaf(zf0, dx, ox), cy0 = fmaf(zf0, dy, oy), cz0 = fmaf(zf0, dz, oz);
    const float cx1 = fmaf(zf1, dx, ox), cy1 = fmaf(zf1, dy, oy), cz1 = fmaf(zf1, dz, oz);
    const float cx2 = fmaf(zf2, dx, ox), cy2 = fmaf(zf2, dy, oy), cz2 = fmaf(zf2, dz, oz);
    float a0 = bb0, a1 = bb1, a2 = bb2, a3 = bb3;
    float e0 = bb0, e1 = bb1, e2 = bb2, e3 = bb3;
    float f0 = bb0, f1 = bb1, f2 = bb2, f3 = bb3;
#pragma unroll 4
    for (int h = 0; h < HID; ++h) {
        const float4 wa = sW1[2 * h], wb = sW1[2 * h + 1], wc = sW2[h];
        const float base = fmaf(vx, wa.w, fmaf(vy, wb.x, fmaf(vz, wb.y, wb.z)));
        float h0 = fmaf(cx0, wa.x, fmaf(cy0, wa.y, fmaf(cz0, wa.z, base)));
        float h1 = fmaf(cx1, wa.x, fmaf(cy1, wa.y, fmaf(cz1, wa.z, base)));
        float h2 = fmaf(cx2, wa.x, fmaf(cy2, wa.y, fmaf(cz2, wa.z, base)));
        h0 = fmaxf(h0, 0.f); h1 = fmaxf(h1, 0.f); h2 = fmaxf(h2, 0.f);
        a0 = fmaf(h0, wc.x, a0); a1 = fmaf(h0, wc.y, a1); a2 = fmaf(h0, wc.z, a2); a3 = fmaf(h0, wc.w, a3);
        e0 = fmaf(h1, wc.x, e0); e1 = fmaf(h1, wc.y, e1); e2 = fmaf(h1, wc.z, e2); e3 = fmaf(h1, wc.w, e3);
        f0 = fmaf(h2, wc.x, f0); f1 = fmaf(h2, wc.y, f1); f2 = fmaf(h2, wc.z, f2); f3 = fmaf(h2, wc.w, f3);
    }
    const float r0 = 1.f / (1.f + expf(-a0)), g0 = 1.f / (1.f + expf(-a1)), b0v = 1.f / (1.f + expf(-a2));
    const float r1 = 1.f / (1.f + expf(-e0)), g1 = 1.f / (1.f + expf(-e1)), b1v = 1.f / (1.f + expf(-e2));
    const float r2 = 1.f / (1.f + expf(-f0)), g2 = 1.f / (1.f + expf(-f1)), b2v = 1.f / (1.f + expf(-f2));
    const float s0 = fmaxf(a3, 0.f), s1 = fmaxf(e3, 0.f), s2 = fmaxf(f3, 0.f);

    const float d0 = (zf1 - zf0) * norm, d1 = (zf2 - zf1) * norm, d2 = (zn2 - zf2) * norm;
    const float al0 = 1.f - expf(-s0 * d0);
    const float al1 = 1.f - expf(-s1 * d1);
    const float al2 = (lane < 63) ? (1.f - expf(-s2 * d2)) : 1.f;
    const float v0 = 1.f - al0 + EPS_T, v1 = 1.f - al1 + EPS_T, v2 = 1.f - al2 + EPS_T;

    float lp = v0 * v1 * v2;
#pragma unroll
    for (int off = 1; off < 64; off <<= 1) {              // inclusive product scan of lane products
        const float q = __shfl_up(lp, off);
        if (lane >= off) lp *= q;
    }
    float ex = __shfl_up(lp, 1);
    if (lane == 0) ex = 1.f;
    const float tr0 = ex, tr1 = ex * v0, tr2 = tr1 * v1;
    const float w0 = al0 * tr0, w1 = al1 * tr1, w2 = al2 * tr2;

    float fr = fmaf(w0, r0, fmaf(w1, r1, w2 * r2));
    float fg = fmaf(w0, g0, fmaf(w1, g1, w2 * g2));
    float fb = fmaf(w0, b0v, fmaf(w1, b1v, w2 * b2v));
    float fa = w0 + w1 + w2;
    float fd = fmaf(w0, zf0, fmaf(w1, zf1, w2 * zf2));
#pragma unroll
    for (int m = 1; m < 64; m <<= 1) {
        fr += __shfl_xor(fr, m); fg += __shfl_xor(fg, m); fb += __shfl_xor(fb, m);
        fa += __shfl_xor(fa, m); fd += __shfl_xor(fd, m);
    }

    if (lane == 0) {
        float* po = out + (size_t)ray * 8;
        po[0] = c_r;
        po[1] = c_g;
        po[2] = c_b;
        po[3] = c_d;
        po[4] = fr + (1.f - fa);
        po[5] = fg + (1.f - fa);
        po[6] = fb + (1.f - fa);
        po[7] = fd;
    }
}

extern "C" void kernel_launch(void* const* d_in, const int* in_sizes, int n_in,
                              void* d_out, int out_size, void* d_ws, size_t ws_size,
                              hipStream_t stream) {
    const float* ro = (const float*)d_in[0];
    const float* rd = (const float*)d_in[1];
    const float* W1 = (const float*)d_in[2];
    const float* b1 = (const float*)d_in[3];
    const float* W2 = (const float*)d_in[4];
    const float* b2 = (const float*)d_in[5];
    float* out = (float*)d_out;
    nerf_kernel<<<dim3(RAYS / 4), dim3(256), 0, stream>>>(ro, rd, W1, b1, W2, b2, out);
}

// Round 5
// 90.259 us; speedup vs baseline: 1.2158x; 1.2158x over previous
//
#include <hip/hip_runtime.h>
#include <math.h>

// One wave per ray, 4 rays/block. R4 minus the analytic merge (bit-consistency
// hazard under ffp-contract): merge uses LDS-staged coarse grid (sZc) exactly
// like the verified R2. Kept from R4: A/B refactor (h = relu(z*B_h + A_h)),
// W2/b2 wave-uniform from global, __expf, acc==1 identity.

#define RAYS   8192
#define NEARP  2.0f
#define FARP   6.0f
#define EPS_T  1e-10f
#define EPS_W  1e-5f
#define F32EPS 1.1920929e-7f

__device__ __forceinline__ float zc(int i) {
    const float t = (float)i * (1.0f / 63.0f);
    return NEARP * (1.0f - t) + FARP * t;
}
__device__ __forceinline__ float sigm(float x) { return 1.f / (1.f + __expf(-x)); }

__global__ __launch_bounds__(256) void nerf_kernel(
    const float* __restrict__ ro, const float* __restrict__ rd,
    const float* __restrict__ W1, const float* __restrict__ b1,
    const float* __restrict__ W2, const float* __restrict__ b2,
    float* __restrict__ out)
{
    __shared__ __align__(16) float sA[4][64];
    __shared__ __align__(16) float sB[4][64];
    __shared__ float sCdf[4][64];    // 63 used
    __shared__ float sZc [4][64];    // coarse z grid (single source of truth for merge)
    __shared__ float sZs [4][128];   // fine z samples (sorted)
    __shared__ float sZf [4][192];   // merged

    const int tid  = threadIdx.x;
    const int w    = tid >> 6;
    const int lane = tid & 63;
    const int ray  = blockIdx.x * 4 + w;

    const float ox = ro[ray * 3 + 0], oy = ro[ray * 3 + 1], oz = ro[ray * 3 + 2];
    const float dx = rd[ray * 3 + 0], dy = rd[ray * 3 + 1], dz = rd[ray * 3 + 2];
    const float norm = sqrtf(dx * dx + dy * dy + dz * dz);
    const float inv  = 1.f / norm;
    const float vx = dx * inv, vy = dy * inv, vz = dz * inv;

    // ---- per-ray A/B precompute: lane h ----
    {
        const float w10 = W1[lane],       w11 = W1[64 + lane],  w12 = W1[128 + lane];
        const float w13 = W1[192 + lane], w14 = W1[256 + lane], w15 = W1[320 + lane];
        float A = b1[lane];
        A = fmaf(vz, w15, A); A = fmaf(vy, w14, A); A = fmaf(vx, w13, A);
        A = fmaf(oz, w12, A); A = fmaf(oy, w11, A); A = fmaf(ox, w10, A);
        const float B = fmaf(dx, w10, fmaf(dy, w11, dz * w12));
        sA[w][lane] = A; sB[w][lane] = B;
    }
    __syncthreads();

    const float4* W2v = (const float4*)W2;
    const float bb0 = b2[0], bb1 = b2[1], bb2 = b2[2], bb3 = b2[3];

    // ---------------- coarse pass ----------------
    const float z = zc(lane);
    sZc[w][lane] = z;
    float o0 = bb0, o1 = bb1, o2 = bb2, o3 = bb3;
#pragma unroll 4
    for (int i = 0; i < 16; ++i) {
        const float4 a4 = ((const float4*)sA[w])[i];
        const float4 b4 = ((const float4*)sB[w])[i];
        const float4 q0 = W2v[4 * i + 0], q1 = W2v[4 * i + 1];
        const float4 q2 = W2v[4 * i + 2], q3 = W2v[4 * i + 3];
        const float h0 = fmaxf(fmaf(z, b4.x, a4.x), 0.f);
        const float h1 = fmaxf(fmaf(z, b4.y, a4.y), 0.f);
        const float h2 = fmaxf(fmaf(z, b4.z, a4.z), 0.f);
        const float h3 = fmaxf(fmaf(z, b4.w, a4.w), 0.f);
        o0 = fmaf(h0, q0.x, o0); o1 = fmaf(h0, q0.y, o1); o2 = fmaf(h0, q0.z, o2); o3 = fmaf(h0, q0.w, o3);
        o0 = fmaf(h1, q1.x, o0); o1 = fmaf(h1, q1.y, o1); o2 = fmaf(h1, q1.z, o2); o3 = fmaf(h1, q1.w, o3);
        o0 = fmaf(h2, q2.x, o0); o1 = fmaf(h2, q2.y, o1); o2 = fmaf(h2, q2.z, o2); o3 = fmaf(h2, q2.w, o3);
        o0 = fmaf(h3, q3.x, o0); o1 = fmaf(h3, q3.y, o1); o2 = fmaf(h3, q3.z, o2); o3 = fmaf(h3, q3.w, o3);
    }
    const float r   = sigm(o0), g = sigm(o1), bl = sigm(o2);
    const float sig = fmaxf(o3, 0.f);

    // volrender (coarse)
    const float znext = __shfl_down(z, 1);                 // lane63 unused
    const float dist  = (znext - z) * norm;
    const float alpha = (lane < 63) ? (1.f - __expf(-sig * dist)) : 1.f;
    const float vfac  = 1.f - alpha + EPS_T;
    float p = vfac;
#pragma unroll
    for (int off = 1; off < 64; off <<= 1) {               // inclusive product scan
        const float q = __shfl_up(p, off);
        if (lane >= off) p *= q;
    }
    float excl = __shfl_up(p, 1);
    if (lane == 0) excl = 1.f;
    const float wgt = alpha * excl;

    // acc == 1 + O(64*EPS_T) (last alpha forced 1) -> white-bkgd term ~0
    float sr = wgt * r, sg = wgt * g, sb = wgt * bl, sd = wgt * z;
#pragma unroll
    for (int m = 1; m < 64; m <<= 1) {
        sr += __shfl_xor(sr, m); sg += __shfl_xor(sg, m);
        sb += __shfl_xor(sb, m); sd += __shfl_xor(sd, m);
    }

    // ---------------- inverse-CDF sampling ----------------
    const float wmraw = __shfl_down(wgt, 1);
    const float wmv   = (lane < 62) ? wmraw : 0.f;          // weights[:,1:-1], 62 bins
    float wsum = wmv;
#pragma unroll
    for (int m = 1; m < 64; m <<= 1) wsum += __shfl_xor(wsum, m);
    const float pad  = fmaxf(0.f, EPS_W - wsum);
    const float wadj = wmv + pad * (1.0f / 62.0f);
    const float wsp  = wsum + pad;
    const float pdf  = (lane < 62) ? (wadj / wsp) : 0.f;
    float ps = pdf;
#pragma unroll
    for (int off = 1; off < 64; off <<= 1) {               // inclusive sum scan
        const float q = __shfl_up(ps, off);
        if (lane >= off) ps += q;
    }
    if (lane < 61)  sCdf[w][lane + 1] = fminf(1.f, ps);    // cdf[1..61]
    if (lane == 61) sCdf[w][0]  = 0.f;
    if (lane == 62) sCdf[w][62] = 1.f;
    __syncthreads();

    float zsv[2];
#pragma unroll
    for (int j = 0; j < 2; ++j) {
        const int f = lane * 2 + j;
        const float u = (float)f * ((1.0f - F32EPS) / 127.0f);
        int lo = 0, hi = 62;                               // cdf[0]=0<=u < 1=cdf[62]
        while (hi - lo > 1) {
            const int mid = (lo + hi) >> 1;
            if (sCdf[w][mid] <= u) lo = mid; else hi = mid;
        }
        const float c0 = sCdf[w][lo], c1 = sCdf[w][lo + 1];
        const float den = c1 - c0;
        float tt = (den > 0.f) ? (u - c0) / den : 0.f;
        tt = fminf(fmaxf(tt, 0.f), 1.f);
        const float za = zc(lo), zb = zc(lo + 1), zd = zc(lo + 2);
        const float bin0 = 0.5f * (za + zb), bin1 = 0.5f * (zb + zd);
        const float zs = fmaf(tt, bin1 - bin0, bin0);
        zsv[j] = zs;
        sZs[w][f] = zs;
    }
    __syncthreads();

    // ---------------- merge (both lists sorted; LDS is the single source of truth
    // so every comparison uses bit-identical values -> provable bijection) -------
    {   // coarse element: pos = lane + count(samples < z)
        int lo = 0, hi = 128;
        while (lo < hi) { const int mid = (lo + hi) >> 1; if (sZs[w][mid] < z) lo = mid + 1; else hi = mid; }
        sZf[w][lane + lo] = z;
    }
#pragma unroll
    for (int j = 0; j < 2; ++j) {   // sample element: pos = idx + count(coarse <= bv)
        const float bv = zsv[j];
        const int f = lane * 2 + j;
        int lo = 0, hi = 64;
        while (lo < hi) { const int mid = (lo + hi) >> 1; if (sZc[w][mid] <= bv) lo = mid + 1; else hi = mid; }
        sZf[w][f + lo] = bv;
    }
    __syncthreads();

    // ---------------- fine pass: 3 samples/lane ----------------
    const float zf0 = sZf[w][3 * lane + 0];
    const float zf1 = sZf[w][3 * lane + 1];
    const float zf2 = sZf[w][3 * lane + 2];
    const float zn2 = sZf[w][min(3 * lane + 3, 191)];      // lane63 value unused

    float a0 = bb0, a1 = bb1, a2 = bb2, a3 = bb3;
    float e0 = bb0, e1 = bb1, e2 = bb2, e3 = bb3;
    float f0 = bb0, f1 = bb1, f2 = bb2, f3 = bb3;
#pragma unroll 2
    for (int i = 0; i < 16; ++i) {
        const float4 a4 = ((const float4*)sA[w])[i];
        const float4 b4 = ((const float4*)sB[w])[i];
        const float4 q0 = W2v[4 * i + 0], q1 = W2v[4 * i + 1];
        const float4 q2 = W2v[4 * i + 2], q3 = W2v[4 * i + 3];
        const float hA0 = fmaxf(fmaf(zf0, b4.x, a4.x), 0.f);
        const float hA1 = fmaxf(fmaf(zf0, b4.y, a4.y), 0.f);
        const float hA2 = fmaxf(fmaf(zf0, b4.z, a4.z), 0.f);
        const float hA3 = fmaxf(fmaf(zf0, b4.w, a4.w), 0.f);
        const float hB0 = fmaxf(fmaf(zf1, b4.x, a4.x), 0.f);
        const float hB1 = fmaxf(fmaf(zf1, b4.y, a4.y), 0.f);
        const float hB2 = fmaxf(fmaf(zf1, b4.z, a4.z), 0.f);
        const float hB3 = fmaxf(fmaf(zf1, b4.w, a4.w), 0.f);
        const float hC0 = fmaxf(fmaf(zf2, b4.x, a4.x), 0.f);
        const float hC1 = fmaxf(fmaf(zf2, b4.y, a4.y), 0.f);
        const float hC2 = fmaxf(fmaf(zf2, b4.z, a4.z), 0.f);
        const float hC3 = fmaxf(fmaf(zf2, b4.w, a4.w), 0.f);
        a0 = fmaf(hA0, q0.x, a0); a1 = fmaf(hA0, q0.y, a1); a2 = fmaf(hA0, q0.z, a2); a3 = fmaf(hA0, q0.w, a3);
        a0 = fmaf(hA1, q1.x, a0); a1 = fmaf(hA1, q1.y, a1); a2 = fmaf(hA1, q1.z, a2); a3 = fmaf(hA1, q1.w, a3);
        a0 = fmaf(hA2, q2.x, a0); a1 = fmaf(hA2, q2.y, a1); a2 = fmaf(hA2, q2.z, a2); a3 = fmaf(hA2, q2.w, a3);
        a0 = fmaf(hA3, q3.x, a0); a1 = fmaf(hA3, q3.y, a1); a2 = fmaf(hA3, q3.z, a2); a3 = fmaf(hA3, q3.w, a3);
        e0 = fmaf(hB0, q0.x, e0); e1 = fmaf(hB0, q0.y, e1); e2 = fmaf(hB0, q0.z, e2); e3 = fmaf(hB0, q0.w, e3);
        e0 = fmaf(hB1, q1.x, e0); e1 = fmaf(hB1, q1.y, e1); e2 = fmaf(hB1, q1.z, e2); e3 = fmaf(hB1, q1.w, e3);
        e0 = fmaf(hB2, q2.x, e0); e1 = fmaf(hB2, q2.y, e1); e2 = fmaf(hB2, q2.z, e2); e3 = fmaf(hB2, q2.w, e3);
        e0 = fmaf(hB3, q3.x, e0); e1 = fmaf(hB3, q3.y, e1); e2 = fmaf(hB3, q3.z, e2); e3 = fmaf(hB3, q3.w, e3);
        f0 = fmaf(hC0, q0.x, f0); f1 = fmaf(hC0, q0.y, f1); f2 = fmaf(hC0, q0.z, f2); f3 = fmaf(hC0, q0.w, f3);
        f0 = fmaf(hC1, q1.x, f0); f1 = fmaf(hC1, q1.y, f1); f2 = fmaf(hC1, q1.z, f2); f3 = fmaf(hC1, q1.w, f3);
        f0 = fmaf(hC2, q2.x, f0); f1 = fmaf(hC2, q2.y, f1); f2 = fmaf(hC2, q2.z, f2); f3 = fmaf(hC2, q2.w, f3);
        f0 = fmaf(hC3, q3.x, f0); f1 = fmaf(hC3, q3.y, f1); f2 = fmaf(hC3, q3.z, f2); f3 = fmaf(hC3, q3.w, f3);
    }
    const float r0s = sigm(a0), g0s = sigm(a1), b0s = sigm(a2), s0 = fmaxf(a3, 0.f);
    const float r1s = sigm(e0), g1s = sigm(e1), b1s = sigm(e2), s1 = fmaxf(e3, 0.f);
    const float r2s = sigm(f0), g2s = sigm(f1), b2s = sigm(f2), s2 = fmaxf(f3, 0.f);

    const float d0 = (zf1 - zf0) * norm, d1 = (zf2 - zf1) * norm, d2 = (zn2 - zf2) * norm;
    const float al0 = 1.f - __expf(-s0 * d0);
    const float al1 = 1.f - __expf(-s1 * d1);
    const float al2 = (lane < 63) ? (1.f - __expf(-s2 * d2)) : 1.f;
    const float v0 = 1.f - al0 + EPS_T, v1 = 1.f - al1 + EPS_T, v2 = 1.f - al2 + EPS_T;

    float lp = v0 * v1 * v2;
#pragma unroll
    for (int off = 1; off < 64; off <<= 1) {               // product scan of lane products
        const float q = __shfl_up(lp, off);
        if (lane >= off) lp *= q;
    }
    float ex = __shfl_up(lp, 1);
    if (lane == 0) ex = 1.f;
    const float tr1 = ex * v0, tr2 = tr1 * v1;
    const float w0 = al0 * ex, w1 = al1 * tr1, w2 = al2 * tr2;

    // fine acc == 1 + O(192*EPS_T) -> white-bkgd term ~0
    float fr = fmaf(w0, r0s, fmaf(w1, r1s, w2 * r2s));
    float fg = fmaf(w0, g0s, fmaf(w1, g1s, w2 * g2s));
    float fb = fmaf(w0, b0s, fmaf(w1, b1s, w2 * b2s));
    float fd = fmaf(w0, zf0, fmaf(w1, zf1, w2 * zf2));
#pragma unroll
    for (int m = 1; m < 64; m <<= 1) {
        fr += __shfl_xor(fr, m); fg += __shfl_xor(fg, m);
        fb += __shfl_xor(fb, m); fd += __shfl_xor(fd, m);
    }

    if (lane == 0) {
        float* po = out + (size_t)ray * 8;
        po[0] = sr; po[1] = sg; po[2] = sb; po[3] = sd;
        po[4] = fr; po[5] = fg; po[6] = fb; po[7] = fd;
    }
}

extern "C" void kernel_launch(void* const* d_in, const int* in_sizes, int n_in,
                              void* d_out, int out_size, void* d_ws, size_t ws_size,
                              hipStream_t stream) {
    const float* ro = (const float*)d_in[0];
    const float* rd = (const float*)d_in[1];
    const float* W1 = (const float*)d_in[2];
    const float* b1 = (const float*)d_in[3];
    const float* W2 = (const float*)d_in[4];
    const float* b2 = (const float*)d_in[5];
    float* out = (float*)d_out;
    nerf_kernel<<<dim3(RAYS / 4), dim3(256), 0, stream>>>(ro, rd, W1, b1, W2, b2, out);
}